// Round 4
// baseline (481.412 us; speedup 1.0000x reference)
//
#include <hip/hip_runtime.h>
#include <hip/hip_bf16.h>
#include <math.h>

// ---------------------------------------------------------------------------
// Live computation (dead-code-eliminated reference):
//   dinv[v]   = rsqrt(indeg(v)+1)
//   aggx      = A_norm @ x                    (A includes self loops)
//   h1s       = relu(aggx @ c1W + c1b) * dinv  (pre-scaled, stored BF16)
//   aggh1     = A_norm @ h1   (== dinv[v]*(sum_in h1s[s] + h1s[v]))
//   h2        = relu([aggh1, aggx] @ c2W + c2b)
//   h4        = relu([x, h2] @ f4W + f4b)
//   out       = sigmoid([x, h4] @ f5W + f5b)
// ---------------------------------------------------------------------------

__device__ __forceinline__ unsigned short f32_to_bf16_rne(float f) {
    unsigned u = __float_as_uint(f);
    return (unsigned short)((u + 0x7fffu + ((u >> 16) & 1u)) >> 16);
}

__global__ __launch_bounds__(256) void hist_kernel(const int* __restrict__ ei,
                                                   int* __restrict__ cnt, int E, int N) {
    int e = blockIdx.x * 256 + threadIdx.x;
    if (e < E) {
        unsigned d = (unsigned)ei[2 * e + 1];
        if (d < (unsigned)N) atomicAdd(&cnt[d], 1);
    }
}

__global__ __launch_bounds__(256) void dinv_xs_kernel(const int* __restrict__ cnt,
                                                      const float* __restrict__ x,
                                                      float* __restrict__ dinv,
                                                      float* __restrict__ xs, int n) {
    int v = blockIdx.x * 256 + threadIdx.x;
    if (v >= n) return;
    float dv = rsqrtf((float)(cnt[v] + 1));
    dinv[v] = dv;
    const float4* x4 = (const float4*)x;
    float4 a = x4[v * 2], b = x4[v * 2 + 1];
    float4* o = (float4*)xs;
    o[v * 2]     = make_float4(a.x * dv, a.y * dv, a.z * dv, a.w * dv);
    o[v * 2 + 1] = make_float4(b.x * dv, b.y * dv, b.z * dv, b.w * dv);
}

// exclusive scan of cnt[0..N-1] (index >= N treated as 0) into rowptr[0..ntot-1]
__global__ __launch_bounds__(1024) void scan1_kernel(const int* __restrict__ cnt,
                                                     int* __restrict__ rowptr,
                                                     int* __restrict__ bsum, int ntot, int N) {
    __shared__ int lds[1024];
    int i = blockIdx.x * 1024 + threadIdx.x;
    int v = (i < N) ? cnt[i] : 0;
    lds[threadIdx.x] = v;
    __syncthreads();
    for (int off = 1; off < 1024; off <<= 1) {
        int y = (threadIdx.x >= off) ? lds[threadIdx.x - off] : 0;
        __syncthreads();
        if (threadIdx.x >= off) lds[threadIdx.x] += y;
        __syncthreads();
    }
    if (i < ntot) rowptr[i] = lds[threadIdx.x] - v;           // exclusive
    if (threadIdx.x == 1023) bsum[blockIdx.x] = lds[1023];    // block total
}

__global__ __launch_bounds__(1024) void scan2_kernel(int* __restrict__ bsum, int B) {
    __shared__ int lds[1024];
    int v = (threadIdx.x < B) ? bsum[threadIdx.x] : 0;
    lds[threadIdx.x] = v;
    __syncthreads();
    for (int off = 1; off < 1024; off <<= 1) {
        int y = (threadIdx.x >= off) ? lds[threadIdx.x - off] : 0;
        __syncthreads();
        if (threadIdx.x >= off) lds[threadIdx.x] += y;
        __syncthreads();
    }
    if (threadIdx.x < B) bsum[threadIdx.x] = lds[threadIdx.x] - v;  // exclusive
}

__global__ __launch_bounds__(256) void scan3_kernel(int* __restrict__ rowptr,
                                                    const int* __restrict__ bsum, int ntot) {
    int i = blockIdx.x * 256 + threadIdx.x;
    if (i < ntot) rowptr[i] += bsum[i >> 10];
}

// XCD-partitioned CSR fill (part = blockIdx & 7 matches the XCD round-robin)
__global__ __launch_bounds__(256) void fill_part_kernel(const int* __restrict__ ei,
                                                        int* __restrict__ cursor,
                                                        int* __restrict__ col,
                                                        int E, int N, int nchunk) {
    int part = blockIdx.x & 7;
    int chunk = blockIdx.x >> 3;
    int lo = (int)(((long long)N * part) >> 3);
    int hi = (int)(((long long)N * (part + 1)) >> 3);
    int stride = nchunk * 256;
    for (int e = chunk * 256 + threadIdx.x; e < E; e += stride) {
        int2 pq = ((const int2*)ei)[e];
        int s = pq.x, d = pq.y;
        if (d >= lo && d < hi) {
            int pos = atomicAdd(&cursor[d], 1);
            col[pos] = ((unsigned)s < (unsigned)N) ? s : 0;
        }
    }
}

// agg over 8 features, thread per node (xs is L2-resident: 3.2 MB)
__global__ __launch_bounds__(256) void agg8_kernel(const float* __restrict__ xs,
                                                   const int* __restrict__ rowptr,
                                                   const int* __restrict__ col,
                                                   const float* __restrict__ dinv,
                                                   float* __restrict__ aggx, int n) {
    int v = blockIdx.x * 256 + threadIdx.x;
    if (v >= n) return;
    const float4* r4 = (const float4*)xs;
    float4 a = make_float4(0, 0, 0, 0), b = make_float4(0, 0, 0, 0);
    int end = rowptr[v + 1];
    for (int j = rowptr[v]; j < end; j++) {
        int s = col[j];
        float4 p = r4[(size_t)s * 2], q = r4[(size_t)s * 2 + 1];
        a.x += p.x; a.y += p.y; a.z += p.z; a.w += p.w;
        b.x += q.x; b.y += q.y; b.z += q.z; b.w += q.w;
    }
    float4 p = r4[(size_t)v * 2], q = r4[(size_t)v * 2 + 1];
    a.x += p.x; a.y += p.y; a.z += p.z; a.w += p.w;
    b.x += q.x; b.y += q.y; b.z += q.z; b.w += q.w;
    float dv = dinv[v];
    float4* o = (float4*)aggx;
    o[(size_t)v * 2]     = make_float4(a.x * dv, a.y * dv, a.z * dv, a.w * dv);
    o[(size_t)v * 2 + 1] = make_float4(b.x * dv, b.y * dv, b.z * dv, b.w * dv);
}

// agg over 128 bf16 features: one wave per node, lane holds 2 features (uint)
__global__ __launch_bounds__(256) void agg128_kernel(const unsigned* __restrict__ rows,
                                                     const int* __restrict__ rowptr,
                                                     const int* __restrict__ col,
                                                     const float* __restrict__ dinv,
                                                     float* __restrict__ out, int n) {
    int v = blockIdx.x * 4 + (threadIdx.x >> 6);
    int lane = threadIdx.x & 63;
    if (v >= n) return;
    float ax = 0.f, ay = 0.f;
    int start = rowptr[v], end = rowptr[v + 1];
    for (int base = start; base < end; base += 64) {
        int m = end - base; if (m > 64) m = 64;
        int si = (lane < m) ? col[base + lane] : 0;
        int t = 0;
        for (; t + 4 <= m; t += 4) {
            int s0 = __shfl(si, t),     s1 = __shfl(si, t + 1);
            int s2 = __shfl(si, t + 2), s3 = __shfl(si, t + 3);
            unsigned u0 = rows[(size_t)s0 * 64 + lane];
            unsigned u1 = rows[(size_t)s1 * 64 + lane];
            unsigned u2 = rows[(size_t)s2 * 64 + lane];
            unsigned u3 = rows[(size_t)s3 * 64 + lane];
            ax += (__uint_as_float(u0 << 16) + __uint_as_float(u1 << 16))
                + (__uint_as_float(u2 << 16) + __uint_as_float(u3 << 16));
            ay += (__uint_as_float(u0 & 0xffff0000u) + __uint_as_float(u1 & 0xffff0000u))
                + (__uint_as_float(u2 & 0xffff0000u) + __uint_as_float(u3 & 0xffff0000u));
        }
        for (; t < m; t++) {
            int s = __shfl(si, t);
            unsigned u = rows[(size_t)s * 64 + lane];
            ax += __uint_as_float(u << 16);
            ay += __uint_as_float(u & 0xffff0000u);
        }
    }
    unsigned us = rows[(size_t)v * 64 + lane];
    ax += __uint_as_float(us << 16);
    ay += __uint_as_float(us & 0xffff0000u);
    float dv = dinv[v];
    ((float2*)out)[(size_t)v * 64 + lane] = make_float2(ax * dv, ay * dv);
}

// Dense layer, register-tiled: out128 = act([A1(K1)|A2(K2)] @ W + b)
// 32 nodes/block, 256 threads; thread = (ng, f8) computes 2 nodes x 8 features.
// Per 4-k step: 2 ds_read_b128 + 8 W float4 loads -> 64 FMA  (FMA:DS = 32:1).
// MODE 0: relu * dinv -> bf16 ; MODE 1: relu -> f32 ;
// MODE 2: relu -> h4, fused f5: out[node] = sigmoid([A1row, h4] @ f5W + f5b)
template <int K1, int K2, int MODE>
__global__ __launch_bounds__(256) void gemm_kernel(
    const float* __restrict__ A1, const float* __restrict__ A2,
    const float* __restrict__ W, const float* __restrict__ bias,
    const float* __restrict__ dinv,
    const float* __restrict__ f5W, const float* __restrict__ f5b,
    void* __restrict__ outv, int n) {
    constexpr int K = K1 + K2;
    constexpr int KP = K + 4;          // padded LDS stride (bank-spread rows)
    constexpr int NPB = 32;
    __shared__ float lds[NPB * KP];
    __shared__ float xdot[NPB];

    int node0 = blockIdx.x * NPB;

    // stage NPB rows of [A1|A2] into LDS
    for (int idx = threadIdx.x; idx < NPB * K; idx += 256) {
        int r = idx / K, k = idx - r * K;
        int node = node0 + r;
        float v = 0.f;
        if (node < n)
            v = (k < K1) ? A1[(size_t)node * K1 + k] : A2[(size_t)node * K2 + (k - K1)];
        lds[r * KP + k] = v;
    }
    __syncthreads();

    int f8 = threadIdx.x & 15;   // feature group: fbase..fbase+7
    int ng = threadIdx.x >> 4;   // node group: rows 2ng, 2ng+1
    int fbase = f8 * 8;

    float acc[2][8];
#pragma unroll
    for (int r = 0; r < 2; r++)
#pragma unroll
        for (int j = 0; j < 8; j++) acc[r][j] = 0.f;

    for (int k = 0; k < K; k += 4) {
        float4 wlo[4], whi[4];
#pragma unroll
        for (int kk = 0; kk < 4; kk++) {
            wlo[kk] = *(const float4*)&W[(size_t)(k + kk) * 128 + fbase];
            whi[kk] = *(const float4*)&W[(size_t)(k + kk) * 128 + fbase + 4];
        }
#pragma unroll
        for (int r = 0; r < 2; r++) {
            float4 a = *(const float4*)&lds[(2 * ng + r) * KP + k];
            float av[4] = {a.x, a.y, a.z, a.w};
#pragma unroll
            for (int kk = 0; kk < 4; kk++) {
                acc[r][0] += av[kk] * wlo[kk].x;
                acc[r][1] += av[kk] * wlo[kk].y;
                acc[r][2] += av[kk] * wlo[kk].z;
                acc[r][3] += av[kk] * wlo[kk].w;
                acc[r][4] += av[kk] * whi[kk].x;
                acc[r][5] += av[kk] * whi[kk].y;
                acc[r][6] += av[kk] * whi[kk].z;
                acc[r][7] += av[kk] * whi[kk].w;
            }
        }
    }

    float4 blo = *(const float4*)&bias[fbase];
    float4 bhi = *(const float4*)&bias[fbase + 4];
    float bv[8] = {blo.x, blo.y, blo.z, blo.w, bhi.x, bhi.y, bhi.z, bhi.w};

    if (MODE == 0) {
        unsigned short* out = (unsigned short*)outv;
#pragma unroll
        for (int r = 0; r < 2; r++) {
            int node = node0 + 2 * ng + r;
            if (node < n) {
                float dv = dinv[node];
                unsigned short u[8];
#pragma unroll
                for (int j = 0; j < 8; j++)
                    u[j] = f32_to_bf16_rne(fmaxf(acc[r][j] + bv[j], 0.f) * dv);
                ulonglong2 pk;
                pk.x = (unsigned long long)u[0] | ((unsigned long long)u[1] << 16)
                     | ((unsigned long long)u[2] << 32) | ((unsigned long long)u[3] << 48);
                pk.y = (unsigned long long)u[4] | ((unsigned long long)u[5] << 16)
                     | ((unsigned long long)u[6] << 32) | ((unsigned long long)u[7] << 48);
                *(ulonglong2*)&out[(size_t)node * 128 + fbase] = pk;
            }
        }
    } else if (MODE == 1) {
        float* out = (float*)outv;
#pragma unroll
        for (int r = 0; r < 2; r++) {
            int node = node0 + 2 * ng + r;
            if (node < n) {
                float4 olo = make_float4(fmaxf(acc[r][0] + bv[0], 0.f),
                                         fmaxf(acc[r][1] + bv[1], 0.f),
                                         fmaxf(acc[r][2] + bv[2], 0.f),
                                         fmaxf(acc[r][3] + bv[3], 0.f));
                float4 ohi = make_float4(fmaxf(acc[r][4] + bv[4], 0.f),
                                         fmaxf(acc[r][5] + bv[5], 0.f),
                                         fmaxf(acc[r][6] + bv[6], 0.f),
                                         fmaxf(acc[r][7] + bv[7], 0.f));
                *(float4*)&out[(size_t)node * 128 + fbase] = olo;
                *(float4*)&out[(size_t)node * 128 + fbase + 4] = ohi;
            }
        }
    } else {
        // MODE 2: fused f5 epilogue.  h4 in regs -> xdot from lds (A1 part) ->
        // overwrite lds with h4 (stride 132) -> per-node wave reduce.
        float h4v[2][8];
#pragma unroll
        for (int r = 0; r < 2; r++)
#pragma unroll
            for (int j = 0; j < 8; j++) h4v[r][j] = fmaxf(acc[r][j] + bv[j], 0.f);

        if (threadIdx.x < NPB) {
            float s = 0.f;
#pragma unroll
            for (int k = 0; k < K1; k++) s += lds[threadIdx.x * KP + k] * f5W[k];
            xdot[threadIdx.x] = s;
        }
        __syncthreads();
#pragma unroll
        for (int r = 0; r < 2; r++) {
            float4 olo = make_float4(h4v[r][0], h4v[r][1], h4v[r][2], h4v[r][3]);
            float4 ohi = make_float4(h4v[r][4], h4v[r][5], h4v[r][6], h4v[r][7]);
            *(float4*)&lds[(2 * ng + r) * 132 + fbase] = olo;
            *(float4*)&lds[(2 * ng + r) * 132 + fbase + 4] = ohi;
        }
        __syncthreads();

        float* out = (float*)outv;
        int lane = threadIdx.x & 63;
        int wv = threadIdx.x >> 6;
        float fb = f5b[0];
        float w5a = f5W[K1 + lane], w5b = f5W[K1 + 64 + lane];
        for (int jj = 0; jj < NPB / 4; jj++) {
            int j = wv * (NPB / 4) + jj;
            int node = node0 + j;
            float p = lds[j * 132 + lane] * w5a + lds[j * 132 + 64 + lane] * w5b;
#pragma unroll
            for (int o = 32; o > 0; o >>= 1) p += __shfl_xor(p, o);
            if (lane == 0 && node < n)
                out[node] = 1.f / (1.f + expf(-(p + xdot[j] + fb)));
        }
    }
}

extern "C" void kernel_launch(void* const* d_in, const int* in_sizes, int n_in,
                              void* d_out, int out_size, void* d_ws, size_t ws_size,
                              hipStream_t stream) {
    const float* x   = (const float*)d_in[0];
    const int*   ei  = (const int*)d_in[1];
    const float* c1W = (const float*)d_in[2];
    const float* c1b = (const float*)d_in[3];
    const float* c2W = (const float*)d_in[4];
    const float* c2b = (const float*)d_in[5];
    const float* f4W = (const float*)d_in[18];
    const float* f4b = (const float*)d_in[19];
    const float* f5W = (const float*)d_in[20];
    const float* f5b = (const float*)d_in[21];
    float* out = (float*)d_out;

    int N = in_sizes[0] / 8;
    int E = in_sizes[1] / 2;

    char* p = (char*)d_ws;
    auto alloc = [&](size_t bytes) {
        char* q = p;
        p += (bytes + 255) & ~(size_t)255;
        return q;
    };
    int*   cnt    = (int*)alloc((size_t)N * 4);
    int*   rowptr = (int*)alloc((size_t)(N + 1) * 4);
    int*   cursor = (int*)alloc((size_t)N * 4);
    int*   bsum   = (int*)alloc(4096);
    float* dinv   = (float*)alloc((size_t)N * 4);
    int*   col    = (int*)alloc((size_t)E * 4);
    float* xs     = (float*)alloc((size_t)N * 8 * 4);
    float* aggx   = (float*)alloc((size_t)N * 8 * 4);
    float* bufA   = (float*)alloc((size_t)N * 128 * 4);  // h1s (bf16), then h2 (f32)
    float* bufB   = (float*)alloc((size_t)N * 128 * 4);  // agg_h1 (f32)

    (void)hipMemsetAsync(cnt, 0, (size_t)N * 4, stream);

    int gE = (E + 255) / 256;
    int gN = (N + 255) / 256;
    hist_kernel<<<gE, 256, 0, stream>>>(ei, cnt, E, N);
    dinv_xs_kernel<<<gN, 256, 0, stream>>>(cnt, x, dinv, xs, N);

    int ntot = N + 1;
    int B = (ntot + 1023) / 1024;
    scan1_kernel<<<B, 1024, 0, stream>>>(cnt, rowptr, bsum, ntot, N);
    scan2_kernel<<<1, 1024, 0, stream>>>(bsum, B);
    scan3_kernel<<<(ntot + 255) / 256, 256, 0, stream>>>(rowptr, bsum, ntot);

    (void)hipMemcpyAsync(cursor, rowptr, (size_t)N * 4, hipMemcpyDeviceToDevice, stream);

    int nchunk = 256;
    fill_part_kernel<<<8 * nchunk, 256, 0, stream>>>(ei, cursor, col, E, N, nchunk);

    agg8_kernel<<<gN, 256, 0, stream>>>(xs, rowptr, col, dinv, aggx, N);

    int gG = (N + 31) / 32;
    // h1s = bf16( relu(aggx @ c1W + c1b) * dinv )
    gemm_kernel<8, 0, 0><<<gG, 256, 0, stream>>>(aggx, nullptr, c1W, c1b, dinv,
                                                 nullptr, nullptr, bufA, N);
    // aggh1 = A_norm @ h1  (bf16 gather, f32 accumulate)
    agg128_kernel<<<(N + 3) / 4, 256, 0, stream>>>((const unsigned*)bufA, rowptr, col,
                                                   dinv, bufB, N);
    // h2 = relu([aggh1, aggx] @ c2W + c2b)   (into bufA; h1s now dead)
    gemm_kernel<128, 8, 1><<<gG, 256, 0, stream>>>(bufB, aggx, c2W, c2b, nullptr,
                                                   nullptr, nullptr, bufA, N);
    // h4 = relu([x, h2] @ f4W + f4b); out = sigmoid([x, h4] @ f5W + f5b)
    gemm_kernel<8, 128, 2><<<gG, 256, 0, stream>>>(x, bufA, f4W, f4b, nullptr,
                                                   f5W, f5b, out, N);
}

// Round 5
// 308.188 us; speedup vs baseline: 1.5621x; 1.5621x over previous
//
#include <hip/hip_runtime.h>
#include <hip/hip_bf16.h>
#include <math.h>

// ---------------------------------------------------------------------------
// Live computation (dead-code-eliminated reference):
//   dinv[v] = rsqrt(indeg(v)+1)
//   aggx    = A_norm @ x
//   h1s     = relu(aggx @ c1W + c1b) * dinv       (bf16)
//   aggh1   = A_norm @ h1
//   h2      = relu([aggh1, aggx] @ c2W + c2b)     (MFMA bf16, K padded to 160)
//   h4      = relu([x, h2] @ f4W + f4b)           (MFMA bf16)
//   out     = sigmoid([x, h4] @ f5W + f5b)        (fused into f4 epilogue)
// ---------------------------------------------------------------------------

typedef __attribute__((ext_vector_type(8))) short short8;
typedef __attribute__((ext_vector_type(4))) float f32x4;

__device__ __forceinline__ unsigned short f32_to_bf16_rne(float f) {
    unsigned u = __float_as_uint(f);
    return (unsigned short)((u + 0x7fffu + ((u >> 16) & 1u)) >> 16);
}

__global__ __launch_bounds__(256) void hist_kernel(const int* __restrict__ ei,
                                                   int* __restrict__ cnt, int E, int N) {
    int e = blockIdx.x * 256 + threadIdx.x;
    if (e < E) {
        unsigned d = (unsigned)ei[2 * e + 1];
        if (d < (unsigned)N) atomicAdd(&cnt[d], 1);
    }
}

// dinv, xs (x*dinv f32), and Abf2 cols 0..7 = bf16(x) + zero tail cols 136..159
__global__ __launch_bounds__(256) void dinv_xs_kernel(const int* __restrict__ cnt,
                                                      const float* __restrict__ x,
                                                      float* __restrict__ dinv,
                                                      float* __restrict__ xs,
                                                      unsigned short* __restrict__ Abf2,
                                                      int n) {
    int v = blockIdx.x * 256 + threadIdx.x;
    if (v >= n) return;
    float dv = rsqrtf((float)(cnt[v] + 1));
    dinv[v] = dv;
    const float4* x4 = (const float4*)x;
    float4 a = x4[v * 2], b = x4[v * 2 + 1];
    float4* o = (float4*)xs;
    o[v * 2]     = make_float4(a.x * dv, a.y * dv, a.z * dv, a.w * dv);
    o[v * 2 + 1] = make_float4(b.x * dv, b.y * dv, b.z * dv, b.w * dv);
    // bf16 raw x into Abf2 row v cols 0..7
    unsigned short u[8] = {f32_to_bf16_rne(a.x), f32_to_bf16_rne(a.y),
                           f32_to_bf16_rne(a.z), f32_to_bf16_rne(a.w),
                           f32_to_bf16_rne(b.x), f32_to_bf16_rne(b.y),
                           f32_to_bf16_rne(b.z), f32_to_bf16_rne(b.w)};
    ulonglong2 pk;
    pk.x = (unsigned long long)u[0] | ((unsigned long long)u[1] << 16)
         | ((unsigned long long)u[2] << 32) | ((unsigned long long)u[3] << 48);
    pk.y = (unsigned long long)u[4] | ((unsigned long long)u[5] << 16)
         | ((unsigned long long)u[6] << 32) | ((unsigned long long)u[7] << 48);
    *(ulonglong2*)&Abf2[(size_t)v * 160] = pk;
    // zero tail cols 136..159 (24 ushorts = 48B)
    ulonglong2 z; z.x = 0ull; z.y = 0ull;
    *(ulonglong2*)&Abf2[(size_t)v * 160 + 136] = z;
    *(ulonglong2*)&Abf2[(size_t)v * 160 + 144] = z;
    *(ulonglong2*)&Abf2[(size_t)v * 160 + 152] = z;
}

// exclusive scan of cnt into rowptr
__global__ __launch_bounds__(1024) void scan1_kernel(const int* __restrict__ cnt,
                                                     int* __restrict__ rowptr,
                                                     int* __restrict__ bsum, int ntot, int N) {
    __shared__ int lds[1024];
    int i = blockIdx.x * 1024 + threadIdx.x;
    int v = (i < N) ? cnt[i] : 0;
    lds[threadIdx.x] = v;
    __syncthreads();
    for (int off = 1; off < 1024; off <<= 1) {
        int y = (threadIdx.x >= off) ? lds[threadIdx.x - off] : 0;
        __syncthreads();
        if (threadIdx.x >= off) lds[threadIdx.x] += y;
        __syncthreads();
    }
    if (i < ntot) rowptr[i] = lds[threadIdx.x] - v;
    if (threadIdx.x == 1023) bsum[blockIdx.x] = lds[1023];
}

__global__ __launch_bounds__(1024) void scan2_kernel(int* __restrict__ bsum, int B) {
    __shared__ int lds[1024];
    int v = (threadIdx.x < B) ? bsum[threadIdx.x] : 0;
    lds[threadIdx.x] = v;
    __syncthreads();
    for (int off = 1; off < 1024; off <<= 1) {
        int y = (threadIdx.x >= off) ? lds[threadIdx.x - off] : 0;
        __syncthreads();
        if (threadIdx.x >= off) lds[threadIdx.x] += y;
        __syncthreads();
    }
    if (threadIdx.x < B) bsum[threadIdx.x] = lds[threadIdx.x] - v;
}

__global__ __launch_bounds__(256) void scan3_kernel(int* __restrict__ rowptr,
                                                    const int* __restrict__ bsum, int ntot) {
    int i = blockIdx.x * 256 + threadIdx.x;
    if (i < ntot) rowptr[i] += bsum[i >> 10];
}

// XCD-partitioned CSR fill (part = blockIdx & 7 matches the XCD round-robin)
__global__ __launch_bounds__(256) void fill_part_kernel(const int* __restrict__ ei,
                                                        int* __restrict__ cursor,
                                                        int* __restrict__ col,
                                                        int E, int N, int nchunk) {
    int part = blockIdx.x & 7;
    int chunk = blockIdx.x >> 3;
    int lo = (int)(((long long)N * part) >> 3);
    int hi = (int)(((long long)N * (part + 1)) >> 3);
    int stride = nchunk * 256;
    for (int e = chunk * 256 + threadIdx.x; e < E; e += stride) {
        int2 pq = ((const int2*)ei)[e];
        int s = pq.x, d = pq.y;
        if (d >= lo && d < hi) {
            int pos = atomicAdd(&cursor[d], 1);
            col[pos] = ((unsigned)s < (unsigned)N) ? s : 0;
        }
    }
}

// agg over 8 features; writes f32 aggx (c1 input) AND bf16 into Abf cols 128..135
// + zero tail cols 136..159.
__global__ __launch_bounds__(256) void agg8_kernel(const float* __restrict__ xs,
                                                   const int* __restrict__ rowptr,
                                                   const int* __restrict__ col,
                                                   const float* __restrict__ dinv,
                                                   float* __restrict__ aggx,
                                                   unsigned short* __restrict__ Abf,
                                                   int n) {
    int v = blockIdx.x * 256 + threadIdx.x;
    if (v >= n) return;
    const float4* r4 = (const float4*)xs;
    float4 a = make_float4(0, 0, 0, 0), b = make_float4(0, 0, 0, 0);
    int end = rowptr[v + 1];
    for (int j = rowptr[v]; j < end; j++) {
        int s = col[j];
        float4 p = r4[(size_t)s * 2], q = r4[(size_t)s * 2 + 1];
        a.x += p.x; a.y += p.y; a.z += p.z; a.w += p.w;
        b.x += q.x; b.y += q.y; b.z += q.z; b.w += q.w;
    }
    float4 p = r4[(size_t)v * 2], q = r4[(size_t)v * 2 + 1];
    a.x += p.x; a.y += p.y; a.z += p.z; a.w += p.w;
    b.x += q.x; b.y += q.y; b.z += q.z; b.w += q.w;
    float dv = dinv[v];
    a = make_float4(a.x * dv, a.y * dv, a.z * dv, a.w * dv);
    b = make_float4(b.x * dv, b.y * dv, b.z * dv, b.w * dv);
    float4* o = (float4*)aggx;
    o[(size_t)v * 2]     = a;
    o[(size_t)v * 2 + 1] = b;
    unsigned short u[8] = {f32_to_bf16_rne(a.x), f32_to_bf16_rne(a.y),
                           f32_to_bf16_rne(a.z), f32_to_bf16_rne(a.w),
                           f32_to_bf16_rne(b.x), f32_to_bf16_rne(b.y),
                           f32_to_bf16_rne(b.z), f32_to_bf16_rne(b.w)};
    ulonglong2 pk;
    pk.x = (unsigned long long)u[0] | ((unsigned long long)u[1] << 16)
         | ((unsigned long long)u[2] << 32) | ((unsigned long long)u[3] << 48);
    pk.y = (unsigned long long)u[4] | ((unsigned long long)u[5] << 16)
         | ((unsigned long long)u[6] << 32) | ((unsigned long long)u[7] << 48);
    *(ulonglong2*)&Abf[(size_t)v * 160 + 128] = pk;
    ulonglong2 z; z.x = 0ull; z.y = 0ull;
    *(ulonglong2*)&Abf[(size_t)v * 160 + 136] = z;
    *(ulonglong2*)&Abf[(size_t)v * 160 + 144] = z;
    *(ulonglong2*)&Abf[(size_t)v * 160 + 152] = z;
}

// agg over 128 bf16 features: one wave per node; writes bf16 into Abf cols 0..127
__global__ __launch_bounds__(256) void agg128_kernel(const unsigned* __restrict__ rows,
                                                     const int* __restrict__ rowptr,
                                                     const int* __restrict__ col,
                                                     const float* __restrict__ dinv,
                                                     unsigned short* __restrict__ Abf,
                                                     int n) {
    int v = blockIdx.x * 4 + (threadIdx.x >> 6);
    int lane = threadIdx.x & 63;
    if (v >= n) return;
    float ax = 0.f, ay = 0.f;
    int start = rowptr[v], end = rowptr[v + 1];
    for (int base = start; base < end; base += 64) {
        int m = end - base; if (m > 64) m = 64;
        int si = (lane < m) ? col[base + lane] : 0;
        int t = 0;
        for (; t + 4 <= m; t += 4) {
            int s0 = __shfl(si, t),     s1 = __shfl(si, t + 1);
            int s2 = __shfl(si, t + 2), s3 = __shfl(si, t + 3);
            unsigned u0 = rows[(size_t)s0 * 64 + lane];
            unsigned u1 = rows[(size_t)s1 * 64 + lane];
            unsigned u2 = rows[(size_t)s2 * 64 + lane];
            unsigned u3 = rows[(size_t)s3 * 64 + lane];
            ax += (__uint_as_float(u0 << 16) + __uint_as_float(u1 << 16))
                + (__uint_as_float(u2 << 16) + __uint_as_float(u3 << 16));
            ay += (__uint_as_float(u0 & 0xffff0000u) + __uint_as_float(u1 & 0xffff0000u))
                + (__uint_as_float(u2 & 0xffff0000u) + __uint_as_float(u3 & 0xffff0000u));
        }
        for (; t < m; t++) {
            int s = __shfl(si, t);
            unsigned u = rows[(size_t)s * 64 + lane];
            ax += __uint_as_float(u << 16);
            ay += __uint_as_float(u & 0xffff0000u);
        }
    }
    unsigned us = rows[(size_t)v * 64 + lane];
    ax += __uint_as_float(us << 16);
    ay += __uint_as_float(us & 0xffff0000u);
    float dv = dinv[v];
    unsigned pk = (unsigned)f32_to_bf16_rne(ax * dv)
                | ((unsigned)f32_to_bf16_rne(ay * dv) << 16);
    ((unsigned*)Abf)[(size_t)v * 80 + lane] = pk;
}

// c1 layer (K=8), fp32 VALU: h1s = bf16(relu(aggx @ c1W + c1b) * dinv)
__global__ __launch_bounds__(256) void gemm8_kernel(
    const float* __restrict__ A1, const float* __restrict__ W,
    const float* __restrict__ bias, const float* __restrict__ dinv,
    unsigned short* __restrict__ out, int n) {
    constexpr int K = 8, KP = 12, NPB = 32;
    __shared__ float lds[NPB * KP];
    int node0 = blockIdx.x * NPB;
    for (int idx = threadIdx.x; idx < NPB * K; idx += 256) {
        int r = idx / K, k = idx - r * K;
        int node = node0 + r;
        lds[r * KP + k] = (node < n) ? A1[(size_t)node * K + k] : 0.f;
    }
    __syncthreads();
    int f8 = threadIdx.x & 15, ng = threadIdx.x >> 4;
    int fbase = f8 * 8;
    float acc[2][8];
#pragma unroll
    for (int r = 0; r < 2; r++)
#pragma unroll
        for (int j = 0; j < 8; j++) acc[r][j] = 0.f;
    for (int k = 0; k < K; k += 4) {
        float4 wlo[4], whi[4];
#pragma unroll
        for (int kk = 0; kk < 4; kk++) {
            wlo[kk] = *(const float4*)&W[(size_t)(k + kk) * 128 + fbase];
            whi[kk] = *(const float4*)&W[(size_t)(k + kk) * 128 + fbase + 4];
        }
#pragma unroll
        for (int r = 0; r < 2; r++) {
            float4 a = *(const float4*)&lds[(2 * ng + r) * KP + k];
            float av[4] = {a.x, a.y, a.z, a.w};
#pragma unroll
            for (int kk = 0; kk < 4; kk++) {
                acc[r][0] += av[kk] * wlo[kk].x; acc[r][1] += av[kk] * wlo[kk].y;
                acc[r][2] += av[kk] * wlo[kk].z; acc[r][3] += av[kk] * wlo[kk].w;
                acc[r][4] += av[kk] * whi[kk].x; acc[r][5] += av[kk] * whi[kk].y;
                acc[r][6] += av[kk] * whi[kk].z; acc[r][7] += av[kk] * whi[kk].w;
            }
        }
    }
    float4 blo = *(const float4*)&bias[fbase];
    float4 bhi = *(const float4*)&bias[fbase + 4];
    float bv[8] = {blo.x, blo.y, blo.z, blo.w, bhi.x, bhi.y, bhi.z, bhi.w};
#pragma unroll
    for (int r = 0; r < 2; r++) {
        int node = node0 + 2 * ng + r;
        if (node < n) {
            float dv = dinv[node];
            unsigned short u[8];
#pragma unroll
            for (int j = 0; j < 8; j++)
                u[j] = f32_to_bf16_rne(fmaxf(acc[r][j] + bv[j], 0.f) * dv);
            ulonglong2 pk;
            pk.x = (unsigned long long)u[0] | ((unsigned long long)u[1] << 16)
                 | ((unsigned long long)u[2] << 32) | ((unsigned long long)u[3] << 48);
            pk.y = (unsigned long long)u[4] | ((unsigned long long)u[5] << 16)
                 | ((unsigned long long)u[6] << 32) | ((unsigned long long)u[7] << 48);
            *(ulonglong2*)&out[(size_t)node * 128 + fbase] = pk;
        }
    }
}

// Pack W[K x 128] f32 (K<=136) into MFMA B-fragment layout, K padded to 160:
// wp[((ks*8+fc)*64+l)*8+i] = bf16(W[32ks + 8*(l>>4) + i][(l&15)+16fc]) or 0 pad.
__global__ __launch_bounds__(256) void pack_w_kernel(const float* __restrict__ W,
                                                     unsigned short* __restrict__ wp, int K) {
    int t = blockIdx.x * 256 + threadIdx.x;
    if (t >= 20480) return;
    int i = t & 7, l = (t >> 3) & 63, fc = (t >> 9) & 7, ks = t >> 12;
    int k = ks * 32 + (l >> 4) * 8 + i;
    int c = (l & 15) + 16 * fc;
    float v = (k < K) ? W[(size_t)k * 128 + c] : 0.f;
    wp[t] = f32_to_bf16_rne(v);
}

// MFMA GEMM: C[N x 128] = A[N x 160 bf16] @ Wpack (+bias, relu)
// block = 256 (4 waves), each wave computes 16 rows x 128 cols, 40 MFMAs.
// MODE 1: store bf16 h2 into Abf2 cols 8..135 (row stride 160)
// MODE 2: fused f5: out[row] = sigmoid(x[row]·f5W[0:8] + h4·f5W[8:136] + f5b)
template <int MODE>
__global__ __launch_bounds__(256) void mfma_gemm(
    const unsigned short* __restrict__ A, const unsigned short* __restrict__ wp,
    const float* __restrict__ bias, const float* __restrict__ x,
    const float* __restrict__ f5W, const float* __restrict__ f5b,
    void* __restrict__ outv, int n) {
    __shared__ float ldsx[64];
    int node0 = blockIdx.x * 64;
    if constexpr (MODE == 2) {
        if (threadIdx.x < 64) {
            int rc = min(node0 + (int)threadIdx.x, n - 1);
            float s = 0.f;
#pragma unroll
            for (int k = 0; k < 8; k++) s += x[(size_t)rc * 8 + k] * f5W[k];
            ldsx[threadIdx.x] = s;
        }
        __syncthreads();
    }
    int wave = threadIdx.x >> 6, lane = threadIdx.x & 63;
    int g = lane >> 4, r = lane & 15;
    int row0 = node0 + wave * 16;
    int arow = min(row0 + r, n - 1);

    short8 a[5];
#pragma unroll
    for (int ks = 0; ks < 5; ks++)
        a[ks] = *(const short8*)&A[(size_t)arow * 160 + ks * 32 + g * 8];

    f32x4 acc[8] = {};
#pragma unroll
    for (int ks = 0; ks < 5; ks++) {
#pragma unroll
        for (int fc = 0; fc < 8; fc++) {
            short8 w = *(const short8*)&wp[(size_t)((ks * 8 + fc) * 64 + lane) * 8];
            acc[fc] = __builtin_amdgcn_mfma_f32_16x16x32_bf16(a[ks], w, acc[fc], 0, 0, 0);
        }
    }

    if constexpr (MODE == 1) {
        unsigned short* out = (unsigned short*)outv;
#pragma unroll
        for (int fc = 0; fc < 8; fc++) {
            int c = r + 16 * fc;
            float bc = bias[c];
#pragma unroll
            for (int v = 0; v < 4; v++) {
                int row = row0 + 4 * g + v;
                if (row < n)
                    out[(size_t)row * 160 + 8 + c] =
                        f32_to_bf16_rne(fmaxf(acc[fc][v] + bc, 0.f));
            }
        }
    } else {
        float plog[4] = {0.f, 0.f, 0.f, 0.f};
#pragma unroll
        for (int fc = 0; fc < 8; fc++) {
            int c = r + 16 * fc;
            float bc = bias[c];
            float w5 = f5W[8 + c];
#pragma unroll
            for (int v = 0; v < 4; v++)
                plog[v] += fmaxf(acc[fc][v] + bc, 0.f) * w5;
        }
#pragma unroll
        for (int m = 1; m < 16; m <<= 1) {
#pragma unroll
            for (int v = 0; v < 4; v++) plog[v] += __shfl_xor(plog[v], m);
        }
        if (r == 0) {
            float* out = (float*)outv;
            float fb = f5b[0];
#pragma unroll
            for (int v = 0; v < 4; v++) {
                int row = row0 + 4 * g + v;
                if (row < n)
                    out[row] = 1.f / (1.f + expf(-(plog[v] + ldsx[wave * 16 + 4 * g + v] + fb)));
            }
        }
    }
}

extern "C" void kernel_launch(void* const* d_in, const int* in_sizes, int n_in,
                              void* d_out, int out_size, void* d_ws, size_t ws_size,
                              hipStream_t stream) {
    const float* x   = (const float*)d_in[0];
    const int*   ei  = (const int*)d_in[1];
    const float* c1W = (const float*)d_in[2];
    const float* c1b = (const float*)d_in[3];
    const float* c2W = (const float*)d_in[4];
    const float* c2b = (const float*)d_in[5];
    const float* f4W = (const float*)d_in[18];
    const float* f4b = (const float*)d_in[19];
    const float* f5W = (const float*)d_in[20];
    const float* f5b = (const float*)d_in[21];
    float* out = (float*)d_out;

    int N = in_sizes[0] / 8;
    int E = in_sizes[1] / 2;

    char* p = (char*)d_ws;
    auto alloc = [&](size_t bytes) {
        char* q = p;
        p += (bytes + 255) & ~(size_t)255;
        return q;
    };
    int*            cnt    = (int*)alloc((size_t)N * 4);
    int*            rowptr = (int*)alloc((size_t)(N + 1) * 4);
    int*            cursor = (int*)alloc((size_t)N * 4);
    int*            bsum   = (int*)alloc(4096);
    float*          dinv   = (float*)alloc((size_t)N * 4);
    int*            col    = (int*)alloc((size_t)E * 4);
    float*          xs     = (float*)alloc((size_t)N * 8 * 4);
    float*          aggx   = (float*)alloc((size_t)N * 8 * 4);
    unsigned short* bufH1  = (unsigned short*)alloc((size_t)N * 128 * 2); // h1s bf16
    unsigned short* Abf    = (unsigned short*)alloc((size_t)N * 160 * 2); // [aggh1|aggx|0]
    unsigned short* Abf2   = (unsigned short*)alloc((size_t)N * 160 * 2); // [x|h2|0]
    unsigned short* wp2    = (unsigned short*)alloc(20480 * 2);
    unsigned short* wp4    = (unsigned short*)alloc(20480 * 2);

    (void)hipMemsetAsync(cnt, 0, (size_t)N * 4, stream);

    int gE = (E + 255) / 256;
    int gN = (N + 255) / 256;
    pack_w_kernel<<<80, 256, 0, stream>>>(c2W, wp2, 136);
    pack_w_kernel<<<80, 256, 0, stream>>>(f4W, wp4, 136);
    hist_kernel<<<gE, 256, 0, stream>>>(ei, cnt, E, N);
    dinv_xs_kernel<<<gN, 256, 0, stream>>>(cnt, x, dinv, xs, Abf2, N);

    int ntot = N + 1;
    int B = (ntot + 1023) / 1024;
    scan1_kernel<<<B, 1024, 0, stream>>>(cnt, rowptr, bsum, ntot, N);
    scan2_kernel<<<1, 1024, 0, stream>>>(bsum, B);
    scan3_kernel<<<(ntot + 255) / 256, 256, 0, stream>>>(rowptr, bsum, ntot);

    (void)hipMemcpyAsync(cursor, rowptr, (size_t)N * 4, hipMemcpyDeviceToDevice, stream);

    int nchunk = 256;
    fill_part_kernel<<<8 * nchunk, 256, 0, stream>>>(ei, cursor, col, E, N, nchunk);

    agg8_kernel<<<gN, 256, 0, stream>>>(xs, rowptr, col, dinv, aggx, Abf, N);

    // h1s = bf16( relu(aggx @ c1W + c1b) * dinv )
    gemm8_kernel<<<(N + 31) / 32, 256, 0, stream>>>(aggx, c1W, c1b, dinv, bufH1, N);

    // aggh1 (bf16) into Abf cols 0..127
    agg128_kernel<<<(N + 3) / 4, 256, 0, stream>>>((const unsigned*)bufH1, rowptr, col,
                                                   dinv, Abf, N);

    int g64 = (N + 63) / 64;
    // h2 = relu([aggh1, aggx] @ c2W + c2b) -> bf16 into Abf2 cols 8..135
    mfma_gemm<1><<<g64, 256, 0, stream>>>(Abf, wp2, c2b, nullptr, nullptr, nullptr,
                                          Abf2, N);
    // h4 = relu([x, h2] @ f4W + f4b); out = sigmoid([x, h4] @ f5W + f5b)
    mfma_gemm<2><<<g64, 256, 0, stream>>>(Abf2, wp4, f4b, x, f5W, f5b, out, N);
}